// Round 2
// baseline (2440.558 us; speedup 1.0000x reference)
//
#include <hip/hip_runtime.h>

#define KCODES 1024
#define DDIM 128
#define HW 64
#define BATCH 32
#define NPIX (BATCH * HW * HW)      // 131072 pixels
#define PLANE (HW * HW)             // 4096
#define BSTRIDE (DDIM * PLANE)      // 524288 floats per batch image
#define MARGIN 1e-4f

// ---------------------------------------------------------------------------
// prep: Bsum[k] = numpy-pairwise sum of codebook[k,:]^2  (fp32, no contraction,
// exact numpy pairwise order for n=128: 8 accumulators, tree combine)
// ---------------------------------------------------------------------------
__global__ __launch_bounds__(256) void prep_kernel(const float* __restrict__ cb,
                                                   float* __restrict__ Bsum) {
#pragma clang fp contract(off)
    int k = blockIdx.x * blockDim.x + threadIdx.x;
    if (k >= KCODES) return;
    const float* row = cb + k * DDIM;
    float r[8];
#pragma unroll
    for (int j = 0; j < 8; ++j) { float x = row[j]; r[j] = x * x; }
#pragma unroll
    for (int i = 8; i < DDIM; i += 8) {
#pragma unroll
        for (int j = 0; j < 8; ++j) { float x = row[i + j]; r[j] = r[j] + x * x; }
    }
    Bsum[k] = ((r[0] + r[1]) + (r[2] + r[3])) + ((r[4] + r[5]) + (r[6] + r[7]));
}

// ---------------------------------------------------------------------------
// phase 1: one wave per (b,h), lane = w. z-row (128 fp32) cached in VGPRs.
// __launch_bounds__(256,1): allow up to 512 VGPRs so zr[128] stays in
// registers (R1 post-mortem: default heuristic capped at 76 VGPRs -> spill,
// VALUBusy 22%). Distances s_k = B_k - 2*dot (fp32, 4 accumulators).
// Track min1/min2; unambiguous -> write codebook row; else -> list.
// ---------------------------------------------------------------------------
__global__ __launch_bounds__(256, 1) void phase1_kernel(
    const float* __restrict__ z, const float* __restrict__ cb,
    const float* __restrict__ Bsum, float* __restrict__ out,
    int* __restrict__ cnt, int* __restrict__ list) {
    int gid = blockIdx.x * blockDim.x + threadIdx.x;
    int wave = gid >> 6;            // 0..2047 = (b,h)
    int lane = gid & 63;            // w
    int b = wave >> 6, h = wave & 63;

    const float* zp = z + (size_t)b * BSTRIDE + h * HW + lane;
    float zr[DDIM];
#pragma unroll
    for (int i = 0; i < DDIM; ++i) zr[i] = zp[(size_t)i * PLANE];

    float min1 = 3.4e38f, min2 = 3.4e38f;
    int idx1 = 0;
    for (int k = 0; k < KCODES; ++k) {
        const float* c = cb + k * DDIM;   // wave-uniform -> scalar loads
        float a0 = 0.f, a1 = 0.f, a2 = 0.f, a3 = 0.f;
#pragma unroll
        for (int i = 0; i < DDIM; i += 4) {
            a0 = __builtin_fmaf(zr[i + 0], c[i + 0], a0);
            a1 = __builtin_fmaf(zr[i + 1], c[i + 1], a1);
            a2 = __builtin_fmaf(zr[i + 2], c[i + 2], a2);
            a3 = __builtin_fmaf(zr[i + 3], c[i + 3], a3);
        }
        float dot = (a0 + a1) + (a2 + a3);
        float dist = Bsum[k] - 2.0f * dot;
        if (dist < min1) { min2 = min1; min1 = dist; idx1 = k; }
        else if (dist < min2) { min2 = dist; }
    }

    // write best guess for every pixel (phase 3 overwrites ambiguous ones)
    float* op = out + (size_t)b * BSTRIDE + h * HW + lane;
    const float* cw = cb + idx1 * DDIM;
#pragma unroll 8
    for (int i = 0; i < DDIM; ++i) op[(size_t)i * PLANE] = cw[i];

    if (min2 - min1 <= MARGIN) {
        int pos = atomicAdd(cnt, 1);
        list[pos] = wave * 64 + lane;   // pixel id in (b,h,w) order
    }
}

// ---------------------------------------------------------------------------
// phase 3: one wave per ambiguous pixel (grid-stride). Lane handles 16 codes.
// R2 restructure: no zr[128] per lane (R1: spilled). Pass A is d-chunked
// (32-float z chunk + 16 running dot accumulators, ~70 VGPRs). numpy-pairwise
// A and fp64 candidate dots re-read z directly (broadcast loads; rare path).
// numpy fp32 emulation:
//   A   = numpy-pairwise sum of z^2 (fp32, no FMA contraction)
//   p   = dot in fp64 (proxy for BLAS fp32 accumulation, error ~1e-9)
//   D_k = fl32( fl32(A + B_k) - fl32(2*p) )
// winner = lexicographic min (D_k, k)  == numpy first-index argmin.
// ---------------------------------------------------------------------------
__global__ __launch_bounds__(256, 2) void phase3_kernel(
    const float* __restrict__ z, const float* __restrict__ cb,
    const float* __restrict__ Bsum, float* __restrict__ out,
    const int* __restrict__ cnt, const int* __restrict__ list) {
    int gid = blockIdx.x * blockDim.x + threadIdx.x;
    int gwave = gid >> 6;
    int lane = gid & 63;
    int nwaves = (gridDim.x * blockDim.x) >> 6;
    int n = *cnt;

    for (int item = gwave; item < n; item += nwaves) {
        int pix = list[item];
        int b = pix >> 12, h = (pix >> 6) & 63, w = pix & 63;
        const float* zp = z + (size_t)b * BSTRIDE + h * HW + w;

        // pass A: running dots for this lane's 16 codes, d-chunked by 32
        float acc[16];
#pragma unroll
        for (int j = 0; j < 16; ++j) acc[j] = 0.f;
#pragma unroll
        for (int c4 = 0; c4 < 4; ++c4) {
            float zc[32];
#pragma unroll
            for (int t = 0; t < 32; ++t) zc[t] = zp[(size_t)(c4 * 32 + t) * PLANE];
#pragma unroll
            for (int j = 0; j < 16; ++j) {
                const float* cr = cb + (lane * 16 + j) * DDIM + c4 * 32;
                float a0 = 0.f, a1 = 0.f, a2 = 0.f, a3 = 0.f;
#pragma unroll
                for (int t = 0; t < 32; t += 4) {
                    a0 = __builtin_fmaf(zc[t + 0], cr[t + 0], a0);
                    a1 = __builtin_fmaf(zc[t + 1], cr[t + 1], a1);
                    a2 = __builtin_fmaf(zc[t + 2], cr[t + 2], a2);
                    a3 = __builtin_fmaf(zc[t + 3], cr[t + 3], a3);
                }
                acc[j] += (a0 + a1) + (a2 + a3);
            }
        }
        float s[16];
        float smin = 3.4e38f;
#pragma unroll
        for (int j = 0; j < 16; ++j) {
            s[j] = Bsum[lane * 16 + j] - 2.0f * acc[j];
            smin = fminf(smin, s[j]);
        }
        for (int off = 32; off > 0; off >>= 1)
            smin = fminf(smin, __shfl_xor(smin, off, 64));

        // A: numpy pairwise of z^2 (no contraction!), direct broadcast loads
        float Apair;
        {
#pragma clang fp contract(off)
            float r[8];
#pragma unroll
            for (int j = 0; j < 8; ++j) { float x = zp[(size_t)j * PLANE]; r[j] = x * x; }
#pragma unroll
            for (int i = 8; i < DDIM; i += 8) {
#pragma unroll
                for (int j = 0; j < 8; ++j) {
                    float x = zp[(size_t)(i + j) * PLANE];
                    r[j] = r[j] + x * x;
                }
            }
            Apair = ((r[0] + r[1]) + (r[2] + r[3])) + ((r[4] + r[5]) + (r[6] + r[7]));
        }

        // pass B: emulate numpy fp32 D for candidates (rare lanes)
        float bd = 3.4e38f; int bk = KCODES;
#pragma unroll 1
        for (int j = 0; j < 16; ++j) {
            if (s[j] <= smin + MARGIN) {
                int k = lane * 16 + j;
                const float* c = cb + k * DDIM;
                double dacc = 0.0;
                for (int i = 0; i < DDIM; ++i)
                    dacc = fma((double)zp[(size_t)i * PLANE], (double)c[i], dacc);
                float u = (float)(2.0 * dacc);
                float t, Dk;
                {
#pragma clang fp contract(off)
                    t = Apair + Bsum[k];
                    Dk = t - u;
                }
                if (Dk < bd || (Dk == bd && k < bk)) { bd = Dk; bk = k; }
            }
        }

        // lexicographic wave reduction (min D, then min k)
        for (int off = 32; off > 0; off >>= 1) {
            float od = __shfl_xor(bd, off, 64);
            int   ok = __shfl_xor(bk, off, 64);
            if (od < bd || (od == bd && ok < bk)) { bd = od; bk = ok; }
        }

        float* op = out + (size_t)b * BSTRIDE + h * HW + w;
        const float* cw = cb + bk * DDIM;
        for (int ci = lane; ci < DDIM; ci += 64)
            op[(size_t)ci * PLANE] = cw[ci];
    }
}

// ---------------------------------------------------------------------------
extern "C" void kernel_launch(void* const* d_in, const int* in_sizes, int n_in,
                              void* d_out, int out_size, void* d_ws, size_t ws_size,
                              hipStream_t stream) {
    const float* z  = (const float*)d_in[0];
    const float* cb = (const float*)d_in[1];
    float* out = (float*)d_out;

    // workspace layout: Bsum[1024] | pad | cnt | list[NPIX]
    float* Bsum = (float*)d_ws;
    int* cnt  = (int*)((char*)d_ws + 4096);
    int* list = (int*)((char*)d_ws + 4096 + 256);

    hipMemsetAsync(cnt, 0, sizeof(int), stream);   // ws is re-poisoned each call
    prep_kernel<<<KCODES / 256, 256, 0, stream>>>(cb, Bsum);
    phase1_kernel<<<NPIX / 256, 256, 0, stream>>>(z, cb, Bsum, out, cnt, list);
    phase3_kernel<<<512, 256, 0, stream>>>(z, cb, Bsum, out, cnt, list);
}

// Round 3
// 504.367 us; speedup vs baseline: 4.8388x; 4.8388x over previous
//
#include <hip/hip_runtime.h>

#define KCODES 1024
#define DDIM 128
#define HW 64
#define NPIX (32 * HW * HW)         // 131072 pixels
#define PLANE (HW * HW)             // 4096
#define BSTRIDE (DDIM * PLANE)      // 524288 floats per batch image
#define MARGIN 6e-5f
// margin budget: numpy fp32 band <=3.2e-5 + phase1 split-bf16 err <=5e-6
//              + phase3 fp32 dot err <=2e-6  => 6e-5 has ~35% headroom

typedef __attribute__((ext_vector_type(8))) short bf16x8;   // MFMA A/B frag
typedef __attribute__((ext_vector_type(4))) float f32x4;    // MFMA C/D frag

__device__ inline unsigned short f2bf(float f) {            // RNE fp32->bf16
    unsigned u = __builtin_bit_cast(unsigned, f);
    unsigned r = u + 0x7FFFu + ((u >> 16) & 1u);
    return (unsigned short)(r >> 16);
}
__device__ inline float bf2f(unsigned short h) {
    unsigned u = ((unsigned)h) << 16;
    return __builtin_bit_cast(float, u);
}

// ---------------------------------------------------------------------------
// prep1: Bsum[k] = numpy-pairwise sum of codebook[k,:]^2 (fp32, contract off)
// ---------------------------------------------------------------------------
__global__ __launch_bounds__(256) void prep1_kernel(const float* __restrict__ cb,
                                                    float* __restrict__ Bsum) {
#pragma clang fp contract(off)
    int k = blockIdx.x * blockDim.x + threadIdx.x;
    if (k >= KCODES) return;
    const float* row = cb + k * DDIM;
    float r0,r1,r2,r3,r4,r5,r6,r7;
    r0 = row[0]*row[0]; r1 = row[1]*row[1]; r2 = row[2]*row[2]; r3 = row[3]*row[3];
    r4 = row[4]*row[4]; r5 = row[5]*row[5]; r6 = row[6]*row[6]; r7 = row[7]*row[7];
#pragma unroll
    for (int i = 8; i < DDIM; i += 8) {
        r0 += row[i+0]*row[i+0]; r1 += row[i+1]*row[i+1];
        r2 += row[i+2]*row[i+2]; r3 += row[i+3]*row[i+3];
        r4 += row[i+4]*row[i+4]; r5 += row[i+5]*row[i+5];
        r6 += row[i+6]*row[i+6]; r7 += row[i+7]*row[i+7];
    }
    Bsum[k] = ((r0+r1)+(r2+r3)) + ((r4+r5)+(r6+r7));
}

// ---------------------------------------------------------------------------
// prep2: split codebook into bf16 hi/lo, stored in MFMA B-fragment order.
// Frag (c=code chunk of 16, s=kstep of 32, t=hi/lo): lane l holds
// B[k_dim = s*32 + (l>>4)*8 + j][n = c*16 + (l&15)], j=0..7 contiguous.
// ushort offset = ((c*4+s)*2+t)*512 + l*8 + j.
// ---------------------------------------------------------------------------
__global__ __launch_bounds__(256) void prep2_kernel(const float* __restrict__ cb,
                                                    unsigned short* __restrict__ bs) {
    int t = blockIdx.x * 256 + threadIdx.x;   // 16384 threads
    int c = t >> 8, s = (t >> 6) & 3, l = t & 63;
    int n = l & 15, q = l >> 4;
    int k = c * 16 + n;
    int d0 = s * 32 + q * 8;
    const float* row = cb + k * DDIM + d0;
    f32x4 f0 = *(const f32x4*)(row);
    f32x4 f1 = *(const f32x4*)(row + 4);
    int fh = ((c * 4 + s) * 2 + 0) * 512 + l * 8;
    int fl = ((c * 4 + s) * 2 + 1) * 512 + l * 8;
#pragma unroll
    for (int e = 0; e < 4; ++e) {
        float a = f0[e];
        unsigned short hb = f2bf(a);
        bs[fh + e] = hb;
        bs[fl + e] = f2bf(a - bf2f(hb));
        float b = f1[e];
        unsigned short hb2 = f2bf(b);
        bs[fh + 4 + e] = hb2;
        bs[fl + 4 + e] = f2bf(b - bf2f(hb2));
    }
}

// ---------------------------------------------------------------------------
// phase1: MFMA distance+argmin. One wg = 4 waves = 64 pixels (one (b,h) row),
// wave wv owns w in [wv*16, wv*16+16). A frag = -2z split bf16 (in VGPRs).
// acc init = Bsum[k] so MFMA output IS the distance. Codebook fragments
// staged through LDS in 32KB groups (4 chunks of 16 codes), shared by the
// 4 waves. min1/min2/idx tracked per lane then merged across 16-lane groups.
// NOTE: no per-lane arrays beyond 4 elements (R1/R2: big arrays -> scratch).
// ---------------------------------------------------------------------------
__global__ __launch_bounds__(256, 4) void phase1_mfma(
    const float* __restrict__ z, const float* __restrict__ cb,
    const unsigned short* __restrict__ bs, const float* __restrict__ Bsum,
    float* __restrict__ out, int* __restrict__ cnt, int* __restrict__ list)
{
    __shared__ __align__(16) float zbuf[64 * 132];   // 33.8 KB; reused for B
    const int tid = threadIdx.x;
    const int wg = blockIdx.x;          // 0..2047 = (b,h)
    const int b = wg >> 6, h = wg & 63;
    const float* zb = z + (size_t)b * BSTRIDE + h * HW;

    // stage -2*z into LDS [w][d], row stride 132 (16B-aligned, 2-way reads)
#pragma unroll
    for (int r = 0; r < 32; ++r) {
        int d = r * 4 + (tid >> 6);
        int w = tid & 63;
        zbuf[w * 132 + d] = -2.0f * zb[(size_t)d * PLANE + w];
    }
    __syncthreads();

    const int lane = tid & 63, wv = tid >> 6;
    const int n = lane & 15, q = lane >> 4;

    // extract A fragments: A[m=lane&15][k=(lane>>4)*8+j], split hi/lo
    bf16x8 zhi[4], zlo[4];
    {
        const f32x4* zv = (const f32x4*)zbuf;       // row stride 33 f32x4
        int rowb = (wv * 16 + n) * 33;
#pragma unroll
        for (int s = 0; s < 4; ++s) {
            f32x4 f0 = zv[rowb + s * 8 + q * 2];
            f32x4 f1 = zv[rowb + s * 8 + q * 2 + 1];
            bf16x8 hi, lo;
#pragma unroll
            for (int e = 0; e < 4; ++e) {
                float a = f0[e];
                unsigned short hb = f2bf(a);
                hi[e] = (short)hb; lo[e] = (short)f2bf(a - bf2f(hb));
                float c2 = f1[e];
                unsigned short hb2 = f2bf(c2);
                hi[4 + e] = (short)hb2; lo[4 + e] = (short)f2bf(c2 - bf2f(hb2));
            }
            zhi[s] = hi; zlo[s] = lo;
        }
    }

    float m1[4], m2[4]; int i1[4];
#pragma unroll
    for (int r = 0; r < 4; ++r) { m1[r] = 3.4e38f; m2[r] = 3.4e38f; i1[r] = 0; }

    const f32x4* gsrc = (const f32x4*)bs;
    f32x4* ldst = (f32x4*)zbuf;
    const bf16x8* bfr = (const bf16x8*)zbuf;

    for (int g = 0; g < 16; ++g) {
        __syncthreads();                      // prior group's reads done
#pragma unroll
        for (int i = 0; i < 8; ++i)           // copy 32KB group (coalesced)
            ldst[i * 256 + tid] = gsrc[g * 2048 + i * 256 + tid];
        __syncthreads();
#pragma unroll
        for (int cc = 0; cc < 4; ++cc) {
            int kcol = (g * 4 + cc) * 16 + n;
            float bsv = Bsum[kcol];
            f32x4 acc = { bsv, bsv, bsv, bsv };
#pragma unroll
            for (int s = 0; s < 4; ++s) {
                bf16x8 bh = bfr[(cc * 8 + s * 2) * 64 + lane];
                bf16x8 bl = bfr[(cc * 8 + s * 2 + 1) * 64 + lane];
                acc = __builtin_amdgcn_mfma_f32_16x16x32_bf16(zhi[s], bh, acc, 0, 0, 0);
                acc = __builtin_amdgcn_mfma_f32_16x16x32_bf16(zlo[s], bh, acc, 0, 0, 0);
                acc = __builtin_amdgcn_mfma_f32_16x16x32_bf16(zhi[s], bl, acc, 0, 0, 0);
            }
            // C/D: col(code)=lane&15, row(pixel)=q*4+r
#pragma unroll
            for (int r = 0; r < 4; ++r) {
                float dv = acc[r];
                m2[r] = fminf(m2[r], fmaxf(m1[r], dv));
                bool lt = dv < m1[r];
                i1[r] = lt ? kcol : i1[r];
                m1[r] = fminf(m1[r], dv);
            }
        }
    }

    // merge across the 16 lanes sharing rows (xor masks stay within group)
#pragma unroll
    for (int mask = 1; mask <= 8; mask <<= 1) {
#pragma unroll
        for (int r = 0; r < 4; ++r) {
            float om1 = __shfl_xor(m1[r], mask, 64);
            float om2 = __shfl_xor(m2[r], mask, 64);
            int   oi1 = __shfl_xor(i1[r], mask, 64);
            float nm2 = fminf(fminf(m2[r], om2), fmaxf(m1[r], om1));
            bool take = (om1 < m1[r]) || (om1 == m1[r] && oi1 < i1[r]);
            i1[r] = take ? oi1 : i1[r];
            m1[r] = fminf(m1[r], om1);
            m2[r] = nm2;
        }
    }

    __syncthreads();                 // all MFMA LDS reads done; reuse zbuf
    int* idxb = (int*)zbuf;
    if (n == 0) {
#pragma unroll
        for (int r = 0; r < 4; ++r) idxb[wv * 16 + q * 4 + r] = i1[r];
    }
    __syncthreads();

    if (n == 0) {                    // ambiguity flags (rare)
#pragma unroll
        for (int r = 0; r < 4; ++r) {
            if (m2[r] - m1[r] <= MARGIN) {
                int pos = atomicAdd(cnt, 1);
                list[pos] = wg * 64 + wv * 16 + q * 4 + r;
            }
        }
    }

    // write guess: lane -> pixel w = wv*16+n, d = dd*16 + q*4 + e
    int widx = idxb[wv * 16 + n];
    const float* crow = cb + widx * DDIM;
    float* ob = out + (size_t)b * BSTRIDE + h * HW + wv * 16 + n;
#pragma unroll
    for (int dd = 0; dd < 8; ++dd) {
        f32x4 c4 = *(const f32x4*)(crow + dd * 16 + q * 4);
        ob[(size_t)(dd * 16 + q * 4 + 0) * PLANE] = c4[0];
        ob[(size_t)(dd * 16 + q * 4 + 1) * PLANE] = c4[1];
        ob[(size_t)(dd * 16 + q * 4 + 2) * PLANE] = c4[2];
        ob[(size_t)(dd * 16 + q * 4 + 3) * PLANE] = c4[3];
    }
}

// ---------------------------------------------------------------------------
// phase3: exact numpy-emulating resolve for ambiguous pixels. One wave/item.
// Lane owns 16 codes, all state in f32x4s (no spillable arrays).
//   A    = numpy-pairwise sum of z^2 (fp32, contract off)
//   p    = dot in fp64 (proxy for BLAS fp32 sgemm)
//   D_k  = fl32( fl32(A + Bsum_k) - fl32(2*p) )
// winner = lexicographic min (D_k, k) == numpy first-index argmin.
// ---------------------------------------------------------------------------
__global__ __launch_bounds__(256, 2) void phase3_kernel(
    const float* __restrict__ z, const float* __restrict__ cb,
    const float* __restrict__ Bsum, float* __restrict__ out,
    const int* __restrict__ cnt, const int* __restrict__ list)
{
    int gid = blockIdx.x * blockDim.x + threadIdx.x;
    int gwave = gid >> 6, lane = gid & 63;
    int nwaves = (gridDim.x * blockDim.x) >> 6;
    int nitems = *cnt;

    for (int item = gwave; item < nitems; item += nwaves) {
        int pix = list[item];
        int b = pix >> 12, h = (pix >> 6) & 63, w = pix & 63;
        const float* zp = z + (size_t)b * BSTRIDE + h * HW + w;
        int k0 = lane * 16;

        f32x4 a0 = {0,0,0,0}, a1 = {0,0,0,0}, a2 = {0,0,0,0}, a3 = {0,0,0,0};
        for (int dc = 0; dc < 32; ++dc) {
            float z0 = zp[(size_t)(dc*4+0)*PLANE];
            float z1 = zp[(size_t)(dc*4+1)*PLANE];
            float z2 = zp[(size_t)(dc*4+2)*PLANE];
            float z3 = zp[(size_t)(dc*4+3)*PLANE];
            const float* cbase = cb + (size_t)k0 * DDIM + dc * 4;
#define DOT4(J, AV, E) { f32x4 c4 = *(const f32x4*)(cbase + (J) * DDIM); \
    AV[E] = __builtin_fmaf(z0, c4[0], __builtin_fmaf(z1, c4[1], \
            __builtin_fmaf(z2, c4[2], __builtin_fmaf(z3, c4[3], AV[E])))); }
            DOT4(0,a0,0)  DOT4(1,a0,1)  DOT4(2,a0,2)  DOT4(3,a0,3)
            DOT4(4,a1,0)  DOT4(5,a1,1)  DOT4(6,a1,2)  DOT4(7,a1,3)
            DOT4(8,a2,0)  DOT4(9,a2,1)  DOT4(10,a2,2) DOT4(11,a2,3)
            DOT4(12,a3,0) DOT4(13,a3,1) DOT4(14,a3,2) DOT4(15,a3,3)
#undef DOT4
        }
        const f32x4* bs4 = (const f32x4*)(Bsum + k0);
        f32x4 s0 = bs4[0] - 2.0f * a0;
        f32x4 s1 = bs4[1] - 2.0f * a1;
        f32x4 s2 = bs4[2] - 2.0f * a2;
        f32x4 s3 = bs4[3] - 2.0f * a3;
        float smin = fminf(fminf(fminf(s0[0],s0[1]),fminf(s0[2],s0[3])),
                    fminf(fminf(fminf(s1[0],s1[1]),fminf(s1[2],s1[3])),
                    fminf(fminf(fminf(s2[0],s2[1]),fminf(s2[2],s2[3])),
                          fminf(fminf(s3[0],s3[1]),fminf(s3[2],s3[3])))));
        for (int off = 32; off > 0; off >>= 1)
            smin = fminf(smin, __shfl_xor(smin, off, 64));

        // A: numpy pairwise of z^2 (no contraction)
        float Apair;
        {
#pragma clang fp contract(off)
            float r0,r1,r2,r3,r4,r5,r6,r7;
            r0 = zp[0*PLANE]*zp[0*PLANE]; r1 = zp[1*PLANE]*zp[1*PLANE];
            r2 = zp[2*PLANE]*zp[2*PLANE]; r3 = zp[3*PLANE]*zp[3*PLANE];
            r4 = zp[4*PLANE]*zp[4*PLANE]; r5 = zp[5*PLANE]*zp[5*PLANE];
            r6 = zp[6*PLANE]*zp[6*PLANE]; r7 = zp[7*PLANE]*zp[7*PLANE];
#pragma unroll
            for (int i = 8; i < DDIM; i += 8) {
                float x0 = zp[(size_t)(i+0)*PLANE], x1 = zp[(size_t)(i+1)*PLANE];
                float x2 = zp[(size_t)(i+2)*PLANE], x3 = zp[(size_t)(i+3)*PLANE];
                float x4 = zp[(size_t)(i+4)*PLANE], x5 = zp[(size_t)(i+5)*PLANE];
                float x6 = zp[(size_t)(i+6)*PLANE], x7 = zp[(size_t)(i+7)*PLANE];
                r0 += x0*x0; r1 += x1*x1; r2 += x2*x2; r3 += x3*x3;
                r4 += x4*x4; r5 += x5*x5; r6 += x6*x6; r7 += x7*x7;
            }
            Apair = ((r0+r1)+(r2+r3)) + ((r4+r5)+(r6+r7));
        }

        float bd = 3.4e38f; int bk = KCODES;
#define CAND(J, SV, E) { float sj = SV[E]; \
    if (sj <= smin + MARGIN) { \
        int k = k0 + (J); const float* c = cb + (size_t)k * DDIM; \
        double dacc = 0.0; \
        for (int i = 0; i < DDIM; ++i) \
            dacc = fma((double)zp[(size_t)i*PLANE], (double)c[i], dacc); \
        float u = (float)(2.0 * dacc); \
        float tt = Apair + Bsum[k];   /* no mul -> no contraction */ \
        float Dk = tt - u; \
        if (Dk < bd || (Dk == bd && k < bk)) { bd = Dk; bk = k; } } }
        CAND(0,s0,0)  CAND(1,s0,1)  CAND(2,s0,2)  CAND(3,s0,3)
        CAND(4,s1,0)  CAND(5,s1,1)  CAND(6,s1,2)  CAND(7,s1,3)
        CAND(8,s2,0)  CAND(9,s2,1)  CAND(10,s2,2) CAND(11,s2,3)
        CAND(12,s3,0) CAND(13,s3,1) CAND(14,s3,2) CAND(15,s3,3)
#undef CAND

        for (int off = 32; off > 0; off >>= 1) {
            float od = __shfl_xor(bd, off, 64);
            int   ok = __shfl_xor(bk, off, 64);
            if (od < bd || (od == bd && ok < bk)) { bd = od; bk = ok; }
        }

        float* op = out + (size_t)b * BSTRIDE + h * HW + w;
        const float* cw = cb + (size_t)bk * DDIM;
        for (int ci = lane; ci < DDIM; ci += 64)
            op[(size_t)ci * PLANE] = cw[ci];
    }
}

// ---------------------------------------------------------------------------
extern "C" void kernel_launch(void* const* d_in, const int* in_sizes, int n_in,
                              void* d_out, int out_size, void* d_ws, size_t ws_size,
                              hipStream_t stream) {
    const float* z  = (const float*)d_in[0];
    const float* cb = (const float*)d_in[1];
    float* out = (float*)d_out;

    // ws layout: Bsum[1024] (4KB) | cnt (4KB pad) | bsplit (512KB) | list (512KB)
    float* Bsum = (float*)d_ws;
    int* cnt = (int*)((char*)d_ws + 4096);
    unsigned short* bsplit = (unsigned short*)((char*)d_ws + 8192);
    int* list = (int*)((char*)d_ws + 8192 + 524288);

    hipMemsetAsync(cnt, 0, sizeof(int), stream);
    prep1_kernel<<<KCODES / 256, 256, 0, stream>>>(cb, Bsum);
    prep2_kernel<<<64, 256, 0, stream>>>(cb, bsplit);
    phase1_mfma<<<NPIX / 64, 256, 0, stream>>>(z, cb, bsplit, Bsum, out, cnt, list);
    phase3_kernel<<<512, 256, 0, stream>>>(z, cb, Bsum, out, cnt, list);
}

// Round 4
// 361.849 us; speedup vs baseline: 6.7447x; 1.3939x over previous
//
#include <hip/hip_runtime.h>

#define KCODES 1024
#define DDIM 128
#define HW 64
#define NPIX (32 * HW * HW)         // 131072 pixels
#define PLANE (HW * HW)             // 4096
#define BSTRIDE (DDIM * PLANE)      // 524288 floats per batch image
#define MARGIN 6e-5f
#define CAP_A 65536
#define CAP_B 8192
// margin budget: numpy fp32 band <=3.2e-5 (two ulp(128)/2 roundings per code
// pair) + phase1 split-bf16 err <=5e-6 + resolve fp32 err <=2e-6 -> 6e-5 safe.

typedef __attribute__((ext_vector_type(8))) short bf16x8;   // MFMA A/B frag
typedef __attribute__((ext_vector_type(4))) float f32x4;    // MFMA C/D frag

__device__ inline unsigned short f2bf(float f) {            // RNE fp32->bf16
    unsigned u = __builtin_bit_cast(unsigned, f);
    unsigned r = u + 0x7FFFu + ((u >> 16) & 1u);
    return (unsigned short)(r >> 16);
}
__device__ inline float bf2f(unsigned short h) {
    unsigned u = ((unsigned)h) << 16;
    return __builtin_bit_cast(float, u);
}

// ---------------------------------------------------------------------------
// prep1: Bsum[k] = numpy-pairwise sum of codebook[k,:]^2 (fp32, contract off)
// ---------------------------------------------------------------------------
__global__ __launch_bounds__(256) void prep1_kernel(const float* __restrict__ cb,
                                                    float* __restrict__ Bsum) {
#pragma clang fp contract(off)
    int k = blockIdx.x * blockDim.x + threadIdx.x;
    if (k >= KCODES) return;
    const float* row = cb + k * DDIM;
    float r0,r1,r2,r3,r4,r5,r6,r7;
    r0 = row[0]*row[0]; r1 = row[1]*row[1]; r2 = row[2]*row[2]; r3 = row[3]*row[3];
    r4 = row[4]*row[4]; r5 = row[5]*row[5]; r6 = row[6]*row[6]; r7 = row[7]*row[7];
#pragma unroll
    for (int i = 8; i < DDIM; i += 8) {
        r0 += row[i+0]*row[i+0]; r1 += row[i+1]*row[i+1];
        r2 += row[i+2]*row[i+2]; r3 += row[i+3]*row[i+3];
        r4 += row[i+4]*row[i+4]; r5 += row[i+5]*row[i+5];
        r6 += row[i+6]*row[i+6]; r7 += row[i+7]*row[i+7];
    }
    Bsum[k] = ((r0+r1)+(r2+r3)) + ((r4+r5)+(r6+r7));
}

// ---------------------------------------------------------------------------
// prep2: split codebook into bf16 hi/lo, stored in MFMA B-fragment order.
// ushort offset = ((c*4+s)*2+t)*512 + l*8 + j  (c=chunk of 16 codes,
// s=kstep of 32, t=hi/lo; lane l holds B[k=s*32+(l>>4)*8+j][n=c*16+(l&15)]).
// ---------------------------------------------------------------------------
__global__ __launch_bounds__(256) void prep2_kernel(const float* __restrict__ cb,
                                                    unsigned short* __restrict__ bs) {
    int t = blockIdx.x * 256 + threadIdx.x;   // 16384 threads
    int c = t >> 8, s = (t >> 6) & 3, l = t & 63;
    int n = l & 15, q = l >> 4;
    int k = c * 16 + n;
    int d0 = s * 32 + q * 8;
    const float* row = cb + k * DDIM + d0;
    f32x4 f0 = *(const f32x4*)(row);
    f32x4 f1 = *(const f32x4*)(row + 4);
    int fh = ((c * 4 + s) * 2 + 0) * 512 + l * 8;
    int fl = ((c * 4 + s) * 2 + 1) * 512 + l * 8;
#pragma unroll
    for (int e = 0; e < 4; ++e) {
        float a = f0[e];
        unsigned short hb = f2bf(a);
        bs[fh + e] = hb;
        bs[fl + e] = f2bf(a - bf2f(hb));
        float b = f1[e];
        unsigned short hb2 = f2bf(b);
        bs[fh + 4 + e] = hb2;
        bs[fl + 4 + e] = f2bf(b - bf2f(hb2));
    }
}

// ---------------------------------------------------------------------------
// phase1: MFMA distance + top-3 argmin. wg = 4 waves = 64 pixels.
// A frag = -2z split bf16; acc init = Bsum[k] -> MFMA output IS the distance.
// Tracks (m1,i1,m2,i2,m3): m2-m1<=MARGIN -> listA{pix,k1,k2};
// additionally m3-m1<=MARGIN -> listB{pix} (full-scan fallback, rare).
// ---------------------------------------------------------------------------
__global__ __launch_bounds__(256, 4) void phase1_mfma(
    const float* __restrict__ z, const float* __restrict__ cb,
    const unsigned short* __restrict__ bs, const float* __restrict__ Bsum,
    float* __restrict__ out, int* __restrict__ cntA, int2* __restrict__ listA,
    int* __restrict__ cntB, int* __restrict__ listB)
{
    __shared__ __align__(16) float zbuf[64 * 132];   // 33.8 KB; reused for B
    const int tid = threadIdx.x;
    const int wg = blockIdx.x;          // 0..2047 = (b,h)
    const int b = wg >> 6, h = wg & 63;
    const float* zb = z + (size_t)b * BSTRIDE + h * HW;

    // stage -2*z into LDS [w][d], row stride 132
#pragma unroll
    for (int r = 0; r < 32; ++r) {
        int d = r * 4 + (tid >> 6);
        int w = tid & 63;
        zbuf[w * 132 + d] = -2.0f * zb[(size_t)d * PLANE + w];
    }
    __syncthreads();

    const int lane = tid & 63, wv = tid >> 6;
    const int n = lane & 15, q = lane >> 4;

    // A fragments: A[m=lane&15][k=(lane>>4)*8+j], split hi/lo
    bf16x8 zhi[4], zlo[4];
    {
        const f32x4* zv = (const f32x4*)zbuf;       // row stride 33 f32x4
        int rowb = (wv * 16 + n) * 33;
#pragma unroll
        for (int s = 0; s < 4; ++s) {
            f32x4 f0 = zv[rowb + s * 8 + q * 2];
            f32x4 f1 = zv[rowb + s * 8 + q * 2 + 1];
            bf16x8 hi, lo;
#pragma unroll
            for (int e = 0; e < 4; ++e) {
                float a = f0[e];
                unsigned short hb = f2bf(a);
                hi[e] = (short)hb; lo[e] = (short)f2bf(a - bf2f(hb));
                float c2 = f1[e];
                unsigned short hb2 = f2bf(c2);
                hi[4 + e] = (short)hb2; lo[4 + e] = (short)f2bf(c2 - bf2f(hb2));
            }
            zhi[s] = hi; zlo[s] = lo;
        }
    }

    float m1[4], m2[4], m3[4]; int i1[4], i2[4];
#pragma unroll
    for (int r = 0; r < 4; ++r) {
        m1[r] = 3.4e38f; m2[r] = 3.4e38f; m3[r] = 3.4e38f; i1[r] = 0; i2[r] = 0;
    }

    const f32x4* gsrc = (const f32x4*)bs;
    f32x4* ldst = (f32x4*)zbuf;
    const bf16x8* bfr = (const bf16x8*)zbuf;

    for (int g = 0; g < 16; ++g) {
        __syncthreads();                      // prior group's reads done
#pragma unroll
        for (int i = 0; i < 8; ++i)           // copy 32KB group (coalesced)
            ldst[i * 256 + tid] = gsrc[g * 2048 + i * 256 + tid];
        __syncthreads();
#pragma unroll
        for (int cc = 0; cc < 4; ++cc) {
            int kcol = (g * 4 + cc) * 16 + n;
            float bsv = Bsum[kcol];
            f32x4 acc = { bsv, bsv, bsv, bsv };
#pragma unroll
            for (int s = 0; s < 4; ++s) {
                bf16x8 bh = bfr[(cc * 8 + s * 2) * 64 + lane];
                bf16x8 bl = bfr[(cc * 8 + s * 2 + 1) * 64 + lane];
                acc = __builtin_amdgcn_mfma_f32_16x16x32_bf16(zhi[s], bh, acc, 0, 0, 0);
                acc = __builtin_amdgcn_mfma_f32_16x16x32_bf16(zlo[s], bh, acc, 0, 0, 0);
                acc = __builtin_amdgcn_mfma_f32_16x16x32_bf16(zhi[s], bl, acc, 0, 0, 0);
            }
            // C/D: col(code)=lane&15, row(pixel)=q*4+r. Top-3 tracking.
#pragma unroll
            for (int r = 0; r < 4; ++r) {
                float dv = acc[r];
                bool lt1 = dv < m1[r];
                bool lt2 = dv < m2[r];
                m3[r] = lt2 ? m2[r] : fminf(m3[r], dv);
                m2[r] = lt1 ? m1[r] : (lt2 ? dv : m2[r]);
                i2[r] = lt1 ? i1[r] : (lt2 ? kcol : i2[r]);
                m1[r] = lt1 ? dv : m1[r];
                i1[r] = lt1 ? kcol : i1[r];
            }
        }
    }

    // merge sorted-3 tuples across the 16 lanes sharing each row
#pragma unroll
    for (int mask = 1; mask <= 8; mask <<= 1) {
#pragma unroll
        for (int r = 0; r < 4; ++r) {
            float b1 = __shfl_xor(m1[r], mask, 64);
            float b2 = __shfl_xor(m2[r], mask, 64);
            float b3 = __shfl_xor(m3[r], mask, 64);
            int  ib1 = __shfl_xor(i1[r], mask, 64);
            int  ib2 = __shfl_xor(i2[r], mask, 64);
            float a1 = m1[r], a2 = m2[r], a3 = m3[r];
            int  ia1 = i1[r], ia2 = i2[r];
            bool bf = (b1 < a1) || (b1 == a1 && ib1 < ia1);
            float x1 = bf ? b1 : a1;  int xi1 = bf ? ib1 : ia1;
            float x2 = bf ? b2 : a2;  int xi2 = bf ? ib2 : ia2;
            float x3 = bf ? b3 : a3;
            float y1 = bf ? a1 : b1;  int yi1 = bf ? ia1 : ib1;
            float y2 = bf ? a2 : b2;
            bool ys = (y1 < x2) || (y1 == x2 && yi1 < xi2);
            m1[r] = x1; i1[r] = xi1;
            m2[r] = ys ? y1 : x2;  i2[r] = ys ? yi1 : xi2;
            m3[r] = ys ? fminf(x2, y2) : fminf(x3, y1);
        }
    }

    __syncthreads();                 // all MFMA LDS reads done; reuse zbuf
    int* idxb = (int*)zbuf;
    if (n == 0) {
#pragma unroll
        for (int r = 0; r < 4; ++r) idxb[wv * 16 + q * 4 + r] = i1[r];
    }
    __syncthreads();

    if (n == 0) {                    // ambiguity records (rare)
#pragma unroll
        for (int r = 0; r < 4; ++r) {
            if (m2[r] - m1[r] <= MARGIN) {
                int pix = wg * 64 + wv * 16 + q * 4 + r;
                int pos = atomicAdd(cntA, 1);
                if (pos < CAP_A) {
                    int2 rec; rec.x = pix; rec.y = i1[r] | (i2[r] << 16);
                    listA[pos] = rec;
                }
                if (m3[r] - m1[r] <= MARGIN) {
                    int pb = atomicAdd(cntB, 1);
                    if (pb < CAP_B) listB[pb] = pix;
                }
            }
        }
    }

    // write guess: lane -> pixel w = wv*16+n, d = dd*16 + q*4 + e
    int widx = idxb[wv * 16 + n];
    const float* crow = cb + widx * DDIM;
    float* ob = out + (size_t)b * BSTRIDE + h * HW + wv * 16 + n;
#pragma unroll
    for (int dd = 0; dd < 8; ++dd) {
        f32x4 c4 = *(const f32x4*)(crow + dd * 16 + q * 4);
        ob[(size_t)(dd * 16 + q * 4 + 0) * PLANE] = c4[0];
        ob[(size_t)(dd * 16 + q * 4 + 1) * PLANE] = c4[1];
        ob[(size_t)(dd * 16 + q * 4 + 2) * PLANE] = c4[2];
        ob[(size_t)(dd * 16 + q * 4 + 3) * PLANE] = c4[3];
    }
}

// ---------------------------------------------------------------------------
// phase3a: resolve 2-candidate ambiguous pixels. One wave per item.
// z row fetched with one parallel 64-lane round trip into LDS; numpy-exact:
//   A    = numpy-pairwise sum of z^2 (fp32, contract off)
//   p    = dot in fp64 (lane-split + shuffle reduce; order-agnostic, err~1e-13)
//   D_k  = fl32( fl32(A + Bsum_k) - fl32(2*p) );  winner = lex min (D, k)
// No __syncthreads in the item loop (waves diverge); within-wave LDS ops are
// in-order on CDNA so write->read needs no barrier.
// ---------------------------------------------------------------------------
__global__ __launch_bounds__(256, 4) void phase3a_kernel(
    const float* __restrict__ z, const float* __restrict__ cb,
    const float* __restrict__ Bsum, float* __restrict__ out,
    const int* __restrict__ cntA, const int2* __restrict__ listA)
{
    __shared__ float zsh[4][128];
    const int tid = threadIdx.x, lane = tid & 63, wv = tid >> 6;
    int gwave = (blockIdx.x * 256 + tid) >> 6;
    int nwaves = gridDim.x * 4;
    int nitems = *cntA; if (nitems > CAP_A) nitems = CAP_A;

    for (int item = gwave; item < nitems; item += nwaves) {
        int2 rec = listA[item];
        int pix = rec.x;
        int k1 = rec.y & 0xFFFF, k2 = rec.y >> 16;
        int b = pix >> 12, h = (pix >> 6) & 63, w = pix & 63;
        const float* zp = z + (size_t)b * BSTRIDE + h * HW + w;

        float za = zp[(size_t)lane * PLANE];
        float zb = zp[(size_t)(lane + 64) * PLANE];
        zsh[wv][lane] = za;
        zsh[wv][lane + 64] = zb;

        // numpy pairwise A from LDS (broadcast reads; all lanes redundant)
        float Apair;
        {
#pragma clang fp contract(off)
            const float* zr = zsh[wv];
            float r0,r1,r2,r3,r4,r5,r6,r7;
            r0 = zr[0]*zr[0]; r1 = zr[1]*zr[1]; r2 = zr[2]*zr[2]; r3 = zr[3]*zr[3];
            r4 = zr[4]*zr[4]; r5 = zr[5]*zr[5]; r6 = zr[6]*zr[6]; r7 = zr[7]*zr[7];
#pragma unroll
            for (int i = 8; i < DDIM; i += 8) {
                r0 += zr[i+0]*zr[i+0]; r1 += zr[i+1]*zr[i+1];
                r2 += zr[i+2]*zr[i+2]; r3 += zr[i+3]*zr[i+3];
                r4 += zr[i+4]*zr[i+4]; r5 += zr[i+5]*zr[i+5];
                r6 += zr[i+6]*zr[i+6]; r7 += zr[i+7]*zr[i+7];
            }
            Apair = ((r0+r1)+(r2+r3)) + ((r4+r5)+(r6+r7));
        }

        // fp64 dots for k1,k2 (coalesced codebook reads)
        const float* c1 = cb + (size_t)k1 * DDIM;
        const float* c2 = cb + (size_t)k2 * DDIM;
        double p1 = fma((double)za, (double)c1[lane],
                        (double)zb * (double)c1[lane + 64]);
        double p2 = fma((double)za, (double)c2[lane],
                        (double)zb * (double)c2[lane + 64]);
        for (int off = 32; off; off >>= 1) {
            p1 += __shfl_xor(p1, off, 64);
            p2 += __shfl_xor(p2, off, 64);
        }
        float u1 = (float)(2.0 * p1), u2 = (float)(2.0 * p2);
        float D1, D2;
        {
#pragma clang fp contract(off)
            float t1 = Apair + Bsum[k1];
            float t2 = Apair + Bsum[k2];
            D1 = t1 - u1; D2 = t2 - u2;
        }
        int wk = (D1 < D2 || (D1 == D2 && k1 < k2)) ? k1 : k2;

        const float* cw = cb + (size_t)wk * DDIM;
        float* op = out + (size_t)b * BSTRIDE + h * HW + w;
        op[(size_t)lane * PLANE] = cw[lane];
        op[(size_t)(lane + 64) * PLANE] = cw[lane + 64];
    }
}

// ---------------------------------------------------------------------------
// phase3b: full-scan numpy-exact resolve for >=3-candidate pixels (rare,
// expected O(10)). One block per item; lane owns 4 codes. Runs AFTER
// phase3a so its writes win.
// ---------------------------------------------------------------------------
__global__ __launch_bounds__(256, 2) void phase3b_kernel(
    const float* __restrict__ z, const float* __restrict__ cb,
    const float* __restrict__ Bsum, float* __restrict__ out,
    const int* __restrict__ cntB, const int* __restrict__ listB)
{
    __shared__ float zr[128];
    __shared__ float sD[256];
    __shared__ int   sK[256];
    const int tid = threadIdx.x;
    int nitems = *cntB; if (nitems > CAP_B) nitems = CAP_B;

    for (int item = blockIdx.x; item < nitems; item += gridDim.x) {
        int pix = listB[item];
        int b = pix >> 12, h = (pix >> 6) & 63, w = pix & 63;
        const float* zp = z + (size_t)b * BSTRIDE + h * HW + w;
        __syncthreads();                       // zr reuse guard
        if (tid < 128) zr[tid] = zp[(size_t)tid * PLANE];
        __syncthreads();

        // fp32 distances for this thread's 4 codes
        float s0v, s1v, s2v, s3v;
#define SDOT(OUT, J) { int k = tid * 4 + (J); const float* c = cb + (size_t)k * DDIM; \
        float a0=0.f,a1=0.f,a2=0.f,a3=0.f; \
        for (int i = 0; i < DDIM; i += 4) { \
            a0 = __builtin_fmaf(zr[i+0], c[i+0], a0); \
            a1 = __builtin_fmaf(zr[i+1], c[i+1], a1); \
            a2 = __builtin_fmaf(zr[i+2], c[i+2], a2); \
            a3 = __builtin_fmaf(zr[i+3], c[i+3], a3); } \
        OUT = Bsum[k] - 2.0f * ((a0+a1)+(a2+a3)); }
        SDOT(s0v, 0) SDOT(s1v, 1) SDOT(s2v, 2) SDOT(s3v, 3)
#undef SDOT
        float lmin = fminf(fminf(s0v, s1v), fminf(s2v, s3v));
        sD[tid] = lmin; __syncthreads();
        for (int st = 128; st; st >>= 1) {
            if (tid < st) sD[tid] = fminf(sD[tid], sD[tid + st]);
            __syncthreads();
        }
        float smin = sD[0];
        __syncthreads();

        // numpy pairwise A (redundant per thread)
        float Apair;
        {
#pragma clang fp contract(off)
            float r0,r1,r2,r3,r4,r5,r6,r7;
            r0 = zr[0]*zr[0]; r1 = zr[1]*zr[1]; r2 = zr[2]*zr[2]; r3 = zr[3]*zr[3];
            r4 = zr[4]*zr[4]; r5 = zr[5]*zr[5]; r6 = zr[6]*zr[6]; r7 = zr[7]*zr[7];
#pragma unroll
            for (int i = 8; i < DDIM; i += 8) {
                r0 += zr[i+0]*zr[i+0]; r1 += zr[i+1]*zr[i+1];
                r2 += zr[i+2]*zr[i+2]; r3 += zr[i+3]*zr[i+3];
                r4 += zr[i+4]*zr[i+4]; r5 += zr[i+5]*zr[i+5];
                r6 += zr[i+6]*zr[i+6]; r7 += zr[i+7]*zr[i+7];
            }
            Apair = ((r0+r1)+(r2+r3)) + ((r4+r5)+(r6+r7));
        }

        float bd = 3.4e38f; int bk = 1 << 30;
#define CAND(SV, J) { if (SV <= smin + MARGIN) { \
        int k = tid * 4 + (J); const float* c = cb + (size_t)k * DDIM; \
        double dacc = 0.0; \
        for (int i = 0; i < DDIM; ++i) dacc = fma((double)zr[i], (double)c[i], dacc); \
        float u = (float)(2.0 * dacc); \
        float tt, Dk; \
        { float tA = Apair + Bsum[k]; tt = tA; } \
        Dk = tt - u; \
        if (Dk < bd || (Dk == bd && k < bk)) { bd = Dk; bk = k; } } }
        CAND(s0v, 0) CAND(s1v, 1) CAND(s2v, 2) CAND(s3v, 3)
#undef CAND
        sD[tid] = bd; sK[tid] = bk; __syncthreads();
        for (int st = 128; st; st >>= 1) {
            if (tid < st) {
                float od = sD[tid + st]; int ok = sK[tid + st];
                if (od < sD[tid] || (od == sD[tid] && ok < sK[tid])) {
                    sD[tid] = od; sK[tid] = ok;
                }
            }
            __syncthreads();
        }
        int wk = sK[0];
        if (tid < 128)
            out[(size_t)b * BSTRIDE + (size_t)tid * PLANE + h * HW + w] =
                cb[(size_t)wk * DDIM + tid];
    }
}

// ---------------------------------------------------------------------------
extern "C" void kernel_launch(void* const* d_in, const int* in_sizes, int n_in,
                              void* d_out, int out_size, void* d_ws, size_t ws_size,
                              hipStream_t stream) {
    const float* z  = (const float*)d_in[0];
    const float* cb = (const float*)d_in[1];
    float* out = (float*)d_out;

    // ws: Bsum 4K | cnts 4K | bsplit 512K | listA 512K (int2) | listB 32K
    float* Bsum = (float*)d_ws;
    int* cntA = (int*)((char*)d_ws + 4096);
    int* cntB = cntA + 1;
    unsigned short* bsplit = (unsigned short*)((char*)d_ws + 8192);
    int2* listA = (int2*)((char*)d_ws + 8192 + 524288);
    int* listB  = (int*)((char*)d_ws + 8192 + 524288 + 524288);

    hipMemsetAsync(cntA, 0, 2 * sizeof(int), stream);
    prep1_kernel<<<KCODES / 256, 256, 0, stream>>>(cb, Bsum);
    prep2_kernel<<<64, 256, 0, stream>>>(cb, bsplit);
    phase1_mfma<<<NPIX / 64, 256, 0, stream>>>(z, cb, bsplit, Bsum, out,
                                               cntA, listA, cntB, listB);
    phase3a_kernel<<<2048, 256, 0, stream>>>(z, cb, Bsum, out, cntA, listA);
    phase3b_kernel<<<256, 256, 0, stream>>>(z, cb, Bsum, out, cntB, listB);
}